// Round 11
// baseline (286.070 us; speedup 1.0000x reference)
//
#include <hip/hip_runtime.h>

#define LEAKY_SLOPE 0.01f
#define BSHIFT 7              // 128 nodes per bucket
#define BNODES 128
#define CHUNK 4096            // edges per chunked block

typedef unsigned short u16;
typedef short short8 __attribute__((ext_vector_type(8)));
typedef float f32x4 __attribute__((ext_vector_type(4)));

__device__ __forceinline__ float leaky_f(float x) { return x > 0.f ? x : LEAKY_SLOPE * x; }

__device__ __forceinline__ float bf2f(u16 b) {
    return __uint_as_float(((unsigned int)b) << 16);
}
__device__ __forceinline__ u16 f2bf(float f) {
    unsigned int u = __float_as_uint(f);
    return (u16)((u + 0x7FFFu + ((u >> 16) & 1u)) >> 16);  // RNE
}
__device__ __forceinline__ float bflo(unsigned int u) { return __uint_as_float(u << 16); }
__device__ __forceinline__ float bfhi(unsigned int u) { return __uint_as_float(u & 0xFFFF0000u); }
__device__ __forceinline__ unsigned int pack2bf(float lo, float hi) {
    return (unsigned int)f2bf(lo) | ((unsigned int)f2bf(hi) << 16);
}

union U16x8 { uint4 q; short8 s; };

// ---------------------------------------------------------------------------
// Merged prep: Mt (THETA⊗W3, transposed bf16), W1t/W2t (transposed bf16).
// ---------------------------------------------------------------------------
__global__ void prep_all(const float* __restrict__ W3,
                         const float* __restrict__ W1_0, const float* __restrict__ W1_1,
                         const float* __restrict__ W2_0, const float* __restrict__ W2_1,
                         u16* __restrict__ Mt, u16* __restrict__ W1t, u16* __restrict__ W2t) {
    int idx = blockIdx.x * blockDim.x + threadIdx.x;
    if (idx < 192 * 64) {
        int c = idx & 63;
        int r = (idx >> 6) & 63;
        int k = idx >> 12;  // 0..2
        const float TH[3][3] = {{3.f, -3.f, 0.75f},
                                {0.f,  3.f, -1.5f},
                                {0.f,  0.f, 0.75f}};
        float v = 0.f;
        #pragma unroll
        for (int t = 0; t < 3; t++) v += TH[t][k] * W3[(t * 64 + r) * 64 + c];
        Mt[c * 192 + k * 64 + r] = f2bf(v);
    }
    if (idx < 2 * 64 * 128) {           // W1t[br][c][k], W1 is [k][c] (128x64)
        int br = idx >> 13;
        int c = (idx >> 7) & 63;
        int k = idx & 127;
        const float* W = br ? W1_1 : W1_0;
        W1t[idx] = f2bf(W[k * 64 + c]);
    }
    if (idx < 2 * 64 * 64) {            // W2t[br][c][k], W2 is [k][c] (64x64)
        int br = idx >> 12;
        int c = (idx >> 6) & 63;
        int k = idx & 63;
        const float* W = br ? W2_1 : W2_0;
        W2t[idx] = f2bf(W[k * 64 + c]);
    }
}

// ---------------------------------------------------------------------------
// K1: per-chunk per-bucket histogram -> global chunkhist (plain stores,
// NO global atomics). Stride fixed at 1024 for coalesced column scans.
// ---------------------------------------------------------------------------
__global__ void bcount_w(const int* __restrict__ dst0, const int* __restrict__ dst1,
                         int* __restrict__ chunkhist, int N, int E) {
    __shared__ int hist[1024];
    int ch = blockIdx.x;
    int e0 = ch * CHUNK;
    int e1 = min(e0 + CHUNK, 2 * E);
    for (int i = threadIdx.x; i < 1024; i += 256) hist[i] = 0;
    __syncthreads();
    for (int e = e0 + threadIdx.x; e < e1; e += 256) {
        int d = (e >= E) ? (N + dst1[e - E]) : dst0[e];
        atomicAdd(&hist[d >> BSHIFT], 1);
    }
    __syncthreads();
    for (int i = threadIdx.x; i < 1024; i += 256)
        chunkhist[ch * 1024 + i] = hist[i];
}

// ---------------------------------------------------------------------------
// K2: one block, thread t owns bucket t. Serial sweep over chunks converts
// chunkhist to per-chunk exclusive bases (within bucket); then block-scan of
// bucket totals -> bbase. rowptr[0] = 0.
// ---------------------------------------------------------------------------
__global__ void bscan2(int* __restrict__ chunkhist, int nch,
                       int* __restrict__ bbase, int* __restrict__ rowptr, int nbuck) {
    __shared__ int sm[1024];
    int t = threadIdx.x;
    int run = 0;
    for (int ch = 0; ch < nch; ch++) {
        int idx = ch * 1024 + t;
        int v = chunkhist[idx];
        chunkhist[idx] = run;
        run += v;
    }
    int total = run;
    sm[t] = total;
    __syncthreads();
    for (int off = 1; off < 1024; off <<= 1) {
        int a = (t >= off) ? sm[t - off] : 0;
        __syncthreads();
        sm[t] += a;
        __syncthreads();
    }
    if (t < nbuck) {
        bbase[t] = sm[t] - total;   // exclusive
        if (t == nbuck - 1) bbase[nbuck] = sm[t];
    }
    if (t == 0) rowptr[0] = 0;
}

// ---------------------------------------------------------------------------
// K3: scatter with precomputed cursors (no histogram pass, no global atomics).
// Payload: (dst & 127) << 17 | global_src.
// ---------------------------------------------------------------------------
__global__ void scatter_nohist(const int* __restrict__ src0, const int* __restrict__ dst0,
                               const int* __restrict__ src1, const int* __restrict__ dst1,
                               const int* __restrict__ bbase, const int* __restrict__ chunkhist,
                               int* __restrict__ ebuf, int N, int E) {
    __shared__ int cur[1024];
    int ch = blockIdx.x;
    int e0 = ch * CHUNK;
    int e1 = min(e0 + CHUNK, 2 * E);
    for (int i = threadIdx.x; i < 1024; i += 256)
        cur[i] = bbase[i] + chunkhist[ch * 1024 + i];
    __syncthreads();
    for (int e = e0 + threadIdx.x; e < e1; e += 256) {
        int s, d;
        if (e >= E) { s = N + src1[e - E]; d = N + dst1[e - E]; }
        else        { s = src0[e];         d = dst0[e]; }
        int b = d >> BSHIFT;
        int pos = atomicAdd(&cur[b], 1);
        ebuf[pos] = ((d & (BNODES - 1)) << 17) | s;
    }
}

// ---------------------------------------------------------------------------
// K4: per-bucket local counting sort -> node-sorted edge array (payload
// src*64), per-node rowptr/dinv/rsb.
// ---------------------------------------------------------------------------
__global__ void bucket_sort(const int* __restrict__ ebuf_in, const int* __restrict__ bbase,
                            int* __restrict__ ebuf_out, int* __restrict__ rowptr,
                            float* __restrict__ dinv, float* __restrict__ rsb, int n2) {
    __shared__ int hist[BNODES];
    __shared__ int scan[BNODES];
    __shared__ int cur[BNODES];
    int b = blockIdx.x;
    int node0 = b << BSHIFT;
    int beg = bbase[b];
    int end = bbase[b + 1];
    int t = threadIdx.x;
    if (t < BNODES) hist[t] = 0;
    __syncthreads();
    for (int e = beg + t; e < end; e += 256)
        atomicAdd(&hist[(unsigned)ebuf_in[e] >> 17], 1);
    __syncthreads();
    if (t < BNODES) scan[t] = hist[t];
    __syncthreads();
    #pragma unroll
    for (int off = 1; off < BNODES; off <<= 1) {
        int a = (t < BNODES && t >= off) ? scan[t - off] : 0;
        __syncthreads();
        if (t < BNODES) scan[t] += a;
        __syncthreads();
    }
    int nvalid = min(BNODES, n2 - node0);
    if (t < nvalid) {
        int d = hist[t];
        int incl = scan[t];
        rowptr[node0 + t + 1] = beg + incl;
        cur[t] = beg + incl - d;
        float df = (float)(d < 1 ? 1 : d);
        float sq = sqrtf(df);
        rsb[node0 + t] = sq;
        dinv[node0 + t] = 1.0f / sq;
    }
    __syncthreads();
    for (int e = beg + t; e < end; e += 256) {
        int p = ebuf_in[e];
        int pos = atomicAdd(&cur[(unsigned)p >> 17], 1);
        ebuf_out[pos] = (p & 0x1FFFF) << 6;
    }
}

// ---------------------------------------------------------------------------
// SpMM (round-9 form: the measured best operating point for the random-gather
// throughput limit). One wave per node, lane = feature; scalar beg/end via
// readfirstlane -> s_load offsets + saddr gathers; 8 gathers in flight.
// ---------------------------------------------------------------------------
__global__ void spmm_s(const u16* __restrict__ Fin, u16* __restrict__ Fout,
                       const int* __restrict__ rowptr, const int* __restrict__ epay,
                       const float* __restrict__ dinv, int n2) {
    int u = (blockIdx.x * blockDim.x + threadIdx.x) >> 6;
    int j = threadIdx.x & 63;
    if (u >= n2) return;
    int beg = __builtin_amdgcn_readfirstlane(rowptr[u]);
    int end = __builtin_amdgcn_readfirstlane(rowptr[u + 1]);
    const u16* base = Fin + j;
    float a0 = 0.f, a1 = 0.f, a2 = 0.f, a3 = 0.f;
    int e = beg;
    for (; e + 8 <= end; e += 8) {
        int o0 = epay[e + 0], o1 = epay[e + 1], o2 = epay[e + 2], o3 = epay[e + 3];
        int o4 = epay[e + 4], o5 = epay[e + 5], o6 = epay[e + 6], o7 = epay[e + 7];
        u16 v0 = base[o0], v1 = base[o1], v2 = base[o2], v3 = base[o3];
        u16 v4 = base[o4], v5 = base[o5], v6 = base[o6], v7 = base[o7];
        a0 += bf2f(v0); a1 += bf2f(v1); a2 += bf2f(v2); a3 += bf2f(v3);
        a0 += bf2f(v4); a1 += bf2f(v5); a2 += bf2f(v6); a3 += bf2f(v7);
    }
    for (; e + 4 <= end; e += 4) {
        u16 v0 = base[epay[e + 0]], v1 = base[epay[e + 1]];
        u16 v2 = base[epay[e + 2]], v3 = base[epay[e + 3]];
        a0 += bf2f(v0); a1 += bf2f(v1); a2 += bf2f(v2); a3 += bf2f(v3);
    }
    for (; e < end; e++) a0 += bf2f(base[epay[e]]);
    float acc = (a0 + a1) + (a2 + a3);
    float di = dinv[u];
    size_t gi = (size_t)u * 64 + j;
    Fout[gi] = f2bf(bf2f(Fin[gi]) - (di * di) * acc);
}

// ---------------------------------------------------------------------------
// Fused 2-layer MLP via MFMA (unchanged).
// ---------------------------------------------------------------------------
__global__ void mlp_mfma(const float* __restrict__ feat0, const float* __restrict__ feat1,
                         const u16* __restrict__ W1t, const u16* __restrict__ W2t,
                         const float* __restrict__ b1_0, const float* __restrict__ b1_1,
                         const float* __restrict__ b2_0, const float* __restrict__ b2_1,
                         const float* __restrict__ dinv, u16* __restrict__ Hs,
                         int N, int GB) {
    __shared__ u16 tls[4][16 * 64];
    int br = (blockIdx.x >= GB) ? 1 : 0;
    int bb = blockIdx.x - br * GB;
    int lane = threadIdx.x & 63;
    int wv = threadIdx.x >> 6;
    int j = lane & 15;
    int kh = lane >> 4;
    int r0 = bb * 64 + wv * 16;
    const float* feat = br ? feat1 : feat0;
    const float* b1 = br ? b1_1 : b1_0;
    const float* b2 = br ? b2_1 : b2_0;
    const u16* w1t = W1t + br * 64 * 128;
    const u16* w2t = W2t + br * 64 * 64;

    int rr = r0 + j;
    int rc = (rr < N) ? rr : N - 1;

    f32x4 acc[4];
    #pragma unroll
    for (int nt = 0; nt < 4; nt++) acc[nt] = (f32x4){0.f, 0.f, 0.f, 0.f};

    #pragma unroll
    for (int ks = 0; ks < 4; ks++) {
        const float* xp = feat + (size_t)rc * 128 + ks * 32 + kh * 8;
        float4 xa = *reinterpret_cast<const float4*>(xp);
        float4 xb = *reinterpret_cast<const float4*>(xp + 4);
        U16x8 ua;
        ua.q.x = pack2bf(xa.x, xa.y);
        ua.q.y = pack2bf(xa.z, xa.w);
        ua.q.z = pack2bf(xb.x, xb.y);
        ua.q.w = pack2bf(xb.z, xb.w);
        #pragma unroll
        for (int nt = 0; nt < 4; nt++) {
            U16x8 ub;
            ub.q = *reinterpret_cast<const uint4*>(w1t + (nt * 16 + j) * 128 + ks * 32 + kh * 8);
            acc[nt] = __builtin_amdgcn_mfma_f32_16x16x32_bf16(ua.s, ub.s, acc[nt], 0, 0, 0);
        }
    }

    char* tl = reinterpret_cast<char*>(tls[wv]);
    #pragma unroll
    for (int nt = 0; nt < 4; nt++) {
        float bv = b1[nt * 16 + j];
        #pragma unroll
        for (int reg = 0; reg < 4; reg++) {
            int row = kh * 4 + reg;
            int byte = (row * 128 + (nt * 16 + j) * 2) ^ ((row & 7) << 4);
            *reinterpret_cast<u16*>(tl + byte) = f2bf(leaky_f(acc[nt][reg] + bv));
        }
    }
    __syncthreads();

    f32x4 acc2[4];
    #pragma unroll
    for (int nt = 0; nt < 4; nt++) acc2[nt] = (f32x4){0.f, 0.f, 0.f, 0.f};
    #pragma unroll
    for (int ks = 0; ks < 2; ks++) {
        int byte = (j * 128 + (ks * 32 + kh * 8) * 2) ^ ((j & 7) << 4);
        U16x8 ua;
        ua.q = *reinterpret_cast<const uint4*>(tl + byte);
        #pragma unroll
        for (int nt = 0; nt < 4; nt++) {
            U16x8 ub;
            ub.q = *reinterpret_cast<const uint4*>(w2t + (nt * 16 + j) * 64 + ks * 32 + kh * 8);
            acc2[nt] = __builtin_amdgcn_mfma_f32_16x16x32_bf16(ua.s, ub.s, acc2[nt], 0, 0, 0);
        }
    }

    int rowbase = r0 + kh * 4;
    #pragma unroll
    for (int reg = 0; reg < 4; reg++) {
        int row = rowbase + reg;
        if (row < N) {
            float di = dinv[br * N + row];
            u16* o = Hs + (size_t)(br * N + row) * 64 + j;
            #pragma unroll
            for (int nt = 0; nt < 4; nt++)
                o[nt * 16] = f2bf(leaky_f(acc2[nt][reg] + b2[nt * 16 + j]) * di);
        }
    }
}

// ---------------------------------------------------------------------------
// Final GEMM via MFMA (unchanged).
// ---------------------------------------------------------------------------
__global__ void gemmF_mfma(const u16* __restrict__ Hs, const u16* __restrict__ F1s,
                           const u16* __restrict__ F2s, const float* __restrict__ rsb,
                           const u16* __restrict__ Mt, const float* __restrict__ b3,
                           float* __restrict__ out, int N) {
    int lane = threadIdx.x & 63;
    int wv = threadIdx.x >> 6;
    int r0 = blockIdx.x * 64 + wv * 16;
    int j = lane & 15;
    int kh = lane >> 4;

    short8 bfrag[6][4];
    #pragma unroll
    for (int nt = 0; nt < 4; nt++) {
        const u16* mrow = Mt + (size_t)(nt * 16 + j) * 192 + kh * 8;
        #pragma unroll
        for (int ks = 0; ks < 6; ks++) {
            U16x8 u;
            u.q = *reinterpret_cast<const uint4*>(mrow + ks * 32);
            bfrag[ks][nt] = u.s;
        }
    }

    int rr = r0 + j;
    int rc = (rr < N) ? rr : N - 1;
    float s0 = rsb[rc];
    float s1 = rsb[N + rc];

    short8 afrag[6];
    #pragma unroll
    for (int ks = 0; ks < 6; ks++) {
        int pa = ks >> 1;
        const u16* P = (pa == 0) ? Hs : (pa == 1) ? F1s : F2s;
        int koff = (ks & 1) * 32 + kh * 8;
        uint4 x0 = *reinterpret_cast<const uint4*>(P + (size_t)rc * 64 + koff);
        uint4 x1 = *reinterpret_cast<const uint4*>(P + ((size_t)N + rc) * 64 + koff);
        U16x8 u;
        u.q.x = pack2bf(s0 * bflo(x0.x) + s1 * bflo(x1.x),
                        s0 * bfhi(x0.x) + s1 * bfhi(x1.x));
        u.q.y = pack2bf(s0 * bflo(x0.y) + s1 * bflo(x1.y),
                        s0 * bfhi(x0.y) + s1 * bfhi(x1.y));
        u.q.z = pack2bf(s0 * bflo(x0.z) + s1 * bflo(x1.z),
                        s0 * bfhi(x0.z) + s1 * bfhi(x1.z));
        u.q.w = pack2bf(s0 * bflo(x0.w) + s1 * bflo(x1.w),
                        s0 * bfhi(x0.w) + s1 * bfhi(x1.w));
        afrag[ks] = u.s;
    }

    f32x4 acc[4];
    #pragma unroll
    for (int nt = 0; nt < 4; nt++) {
        float bv = 2.f * b3[nt * 16 + j];
        acc[nt] = (f32x4){bv, bv, bv, bv};
    }
    #pragma unroll
    for (int nt = 0; nt < 4; nt++) {
        #pragma unroll
        for (int ks = 0; ks < 6; ks++) {
            acc[nt] = __builtin_amdgcn_mfma_f32_16x16x32_bf16(
                afrag[ks], bfrag[ks][nt], acc[nt], 0, 0, 0);
        }
    }

    int rbase = r0 + kh * 4;
    #pragma unroll
    for (int reg = 0; reg < 4; reg++) {
        int row = rbase + reg;
        if (row < N) {
            float* o = out + (size_t)row * 64 + j;
            #pragma unroll
            for (int nt = 0; nt < 4; nt++)
                o[nt * 16] = leaky_f(acc[nt][reg]);
        }
    }
}

// ---------------------------------------------------------------------------
extern "C" void kernel_launch(void* const* d_in, const int* in_sizes, int n_in,
                              void* d_out, int out_size, void* d_ws, size_t ws_size,
                              hipStream_t stream) {
    const int N = in_sizes[0] / 128;
    const int E = in_sizes[2];
    const int N2 = 2 * N;
    const int NBUCK = (N2 + BNODES - 1) >> BSHIFT;
    const int NCH = (2 * E + CHUNK - 1) / CHUNK;

    const float* feat0 = (const float*)d_in[0];
    const float* feat1 = (const float*)d_in[1];
    const int*   src0  = (const int*)d_in[2];
    const int*   dst0  = (const int*)d_in[3];
    const int*   src1  = (const int*)d_in[4];
    const int*   dst1  = (const int*)d_in[5];
    const float* W1_0  = (const float*)d_in[6];
    const float* b1_0  = (const float*)d_in[7];
    const float* W2_0  = (const float*)d_in[8];
    const float* b2_0  = (const float*)d_in[9];
    const float* W1_1  = (const float*)d_in[10];
    const float* b1_1  = (const float*)d_in[11];
    const float* W2_1  = (const float*)d_in[12];
    const float* b2_1  = (const float*)d_in[13];
    const float* W3    = (const float*)d_in[14];
    const float* b3    = (const float*)d_in[15];
    float* out = (float*)d_out;

    char* p = (char*)d_ws;
    auto alloc = [&](size_t bytes) -> char* {
        char* r = p;
        p += (bytes + 255) & ~(size_t)255;
        return r;
    };
    u16*   Mt        = (u16*)alloc((size_t)64 * 192 * 2);
    u16*   W1t       = (u16*)alloc((size_t)2 * 64 * 128 * 2);
    u16*   W2t       = (u16*)alloc((size_t)2 * 64 * 64 * 2);
    u16*   Hs        = (u16*)alloc((size_t)N2 * 64 * 2);
    u16*   F1s       = (u16*)alloc((size_t)N2 * 64 * 2);
    u16*   F2s       = (u16*)alloc((size_t)N2 * 64 * 2);
    float* dinv      = (float*)alloc((size_t)N2 * 4);
    float* rsb       = (float*)alloc((size_t)N2 * 4);
    int*   rowptr    = (int*)alloc((size_t)(N2 + 1) * 4);
    int*   bbase     = (int*)alloc((size_t)(NBUCK + 1) * 4);
    int*   chunkhist = (int*)alloc((size_t)NCH * 1024 * 4);
    int*   ebuf1     = (int*)alloc((size_t)2 * E * 4);
    int*   ebuf2     = (int*)alloc((size_t)2 * E * 4);
    (void)ws_size; (void)n_in; (void)out_size;

    const int GB64 = (N + 63) / 64;

    prep_all<<<(16384 + 255) / 256, 256, 0, stream>>>(W3, W1_0, W1_1, W2_0, W2_1, Mt, W1t, W2t);

    // --- graph build: chunk-hist -> column scan -> cursor scatter -> local sort ---
    bcount_w<<<NCH, 256, 0, stream>>>(dst0, dst1, chunkhist, N, E);
    bscan2<<<1, 1024, 0, stream>>>(chunkhist, NCH, bbase, rowptr, NBUCK);
    scatter_nohist<<<NCH, 256, 0, stream>>>(src0, dst0, src1, dst1, bbase, chunkhist,
                                            ebuf1, N, E);
    bucket_sort<<<NBUCK, 256, 0, stream>>>(ebuf1, bbase, ebuf2, rowptr, dinv, rsb, N2);

    // --- fused MLP (both branches), MFMA ---
    mlp_mfma<<<2 * GB64, 256, 0, stream>>>(feat0, feat1, W1t, W2t,
                                           b1_0, b1_1, b2_0, b2_1, dinv, Hs, N, GB64);

    // --- polynomial propagation (bf16, node-sorted CSR) ---
    spmm_s<<<(N2 * 64 + 255) / 256, 256, 0, stream>>>(Hs, F1s, rowptr, ebuf2, dinv, N2);
    spmm_s<<<(N2 * 64 + 255) / 256, 256, 0, stream>>>(F1s, F2s, rowptr, ebuf2, dinv, N2);

    // --- final GEMM via MFMA, branch-folded ---
    gemmF_mfma<<<(N + 63) / 64, 256, 0, stream>>>(Hs, F1s, F2s, rsb, Mt, b3, out, N);
}

// Round 12
// 192.104 us; speedup vs baseline: 1.4891x; 1.4891x over previous
//
#include <hip/hip_runtime.h>

#define LEAKY_SLOPE 0.01f
#define BSHIFT 7              // 128 nodes per bucket
#define BNODES 128
#define CHUNK 4096            // edges per chunked block

typedef unsigned short u16;
typedef short short8 __attribute__((ext_vector_type(8)));
typedef float f32x4 __attribute__((ext_vector_type(4)));

__device__ __forceinline__ float leaky_f(float x) { return x > 0.f ? x : LEAKY_SLOPE * x; }

__device__ __forceinline__ float bf2f(u16 b) {
    return __uint_as_float(((unsigned int)b) << 16);
}
__device__ __forceinline__ u16 f2bf(float f) {
    unsigned int u = __float_as_uint(f);
    return (u16)((u + 0x7FFFu + ((u >> 16) & 1u)) >> 16);  // RNE
}
__device__ __forceinline__ float bflo(unsigned int u) { return __uint_as_float(u << 16); }
__device__ __forceinline__ float bfhi(unsigned int u) { return __uint_as_float(u & 0xFFFF0000u); }
__device__ __forceinline__ unsigned int pack2bf(float lo, float hi) {
    return (unsigned int)f2bf(lo) | ((unsigned int)f2bf(hi) << 16);
}

union U16x8 { uint4 q; short8 s; };

// ---------------------------------------------------------------------------
// Merged prep: Mt (THETA⊗W3, transposed bf16), W1t/W2t (transposed bf16),
// bcnt zeroing.
// ---------------------------------------------------------------------------
__global__ void prep_all(const float* __restrict__ W3,
                         const float* __restrict__ W1_0, const float* __restrict__ W1_1,
                         const float* __restrict__ W2_0, const float* __restrict__ W2_1,
                         u16* __restrict__ Mt, u16* __restrict__ W1t, u16* __restrict__ W2t,
                         int* __restrict__ bcnt, int nbuck) {
    int idx = blockIdx.x * blockDim.x + threadIdx.x;
    if (idx < 192 * 64) {
        int c = idx & 63;
        int r = (idx >> 6) & 63;
        int k = idx >> 12;  // 0..2
        const float TH[3][3] = {{3.f, -3.f, 0.75f},
                                {0.f,  3.f, -1.5f},
                                {0.f,  0.f, 0.75f}};
        float v = 0.f;
        #pragma unroll
        for (int t = 0; t < 3; t++) v += TH[t][k] * W3[(t * 64 + r) * 64 + c];
        Mt[c * 192 + k * 64 + r] = f2bf(v);
    }
    if (idx < 2 * 64 * 128) {           // W1t[br][c][k], W1 is [k][c] (128x64)
        int br = idx >> 13;
        int c = (idx >> 7) & 63;
        int k = idx & 127;
        const float* W = br ? W1_1 : W1_0;
        W1t[idx] = f2bf(W[k * 64 + c]);
    }
    if (idx < 2 * 64 * 64) {            // W2t[br][c][k], W2 is [k][c] (64x64)
        int br = idx >> 12;
        int c = (idx >> 6) & 63;
        int k = idx & 63;
        const float* W = br ? W2_1 : W2_0;
        W2t[idx] = f2bf(W[k * 64 + c]);
    }
    if (idx < nbuck) bcnt[idx] = 0;
}

// ---------------------------------------------------------------------------
// Graph build (round-10 proven form): bucket counts (global atomic) -> scan
// -> clustered scatter (LDS hist + atomic segment reserve) -> local sort.
// ---------------------------------------------------------------------------
__global__ void bcount(const int* __restrict__ dst0, const int* __restrict__ dst1,
                       int* __restrict__ bcnt, int N, int E, int nbuck) {
    __shared__ int hist[1024];
    int e0 = blockIdx.x * CHUNK;
    int e1 = min(e0 + CHUNK, 2 * E);
    for (int i = threadIdx.x; i < nbuck; i += 256) hist[i] = 0;
    __syncthreads();
    for (int e = e0 + threadIdx.x; e < e1; e += 256) {
        int d = (e >= E) ? (N + dst1[e - E]) : dst0[e];
        atomicAdd(&hist[d >> BSHIFT], 1);
    }
    __syncthreads();
    for (int i = threadIdx.x; i < nbuck; i += 256) {
        int c = hist[i];
        if (c > 0) atomicAdd(&bcnt[i], c);
    }
}

__global__ void bscan(const int* __restrict__ bcnt, int* __restrict__ bbase,
                      int* __restrict__ bcursor, int* __restrict__ rowptr, int nbuck) {
    __shared__ int sm[1024];
    int t = threadIdx.x;
    int v = (t < nbuck) ? bcnt[t] : 0;
    sm[t] = v;
    __syncthreads();
    for (int off = 1; off < 1024; off <<= 1) {
        int a = (t >= off) ? sm[t - off] : 0;
        __syncthreads();
        sm[t] += a;
        __syncthreads();
    }
    if (t < nbuck) {
        int excl = sm[t] - v;
        bbase[t] = excl;
        bcursor[t] = excl;
        if (t == nbuck - 1) bbase[nbuck] = sm[t];
    }
    if (t == 0) rowptr[0] = 0;
}

__global__ void bucket_scatter(const int* __restrict__ src0, const int* __restrict__ dst0,
                               const int* __restrict__ src1, const int* __restrict__ dst1,
                               int* __restrict__ bcursor, int* __restrict__ ebuf,
                               int N, int E, int nbuck) {
    __shared__ int hist[1024];
    __shared__ int cur[1024];
    int e0 = blockIdx.x * CHUNK;
    int e1 = min(e0 + CHUNK, 2 * E);
    for (int i = threadIdx.x; i < nbuck; i += 256) hist[i] = 0;
    __syncthreads();
    for (int e = e0 + threadIdx.x; e < e1; e += 256) {
        int d = (e >= E) ? (N + dst1[e - E]) : dst0[e];
        atomicAdd(&hist[d >> BSHIFT], 1);
    }
    __syncthreads();
    for (int i = threadIdx.x; i < nbuck; i += 256) {
        int c = hist[i];
        cur[i] = (c > 0) ? atomicAdd(&bcursor[i], c) : 0;
    }
    __syncthreads();
    for (int e = e0 + threadIdx.x; e < e1; e += 256) {
        int s, d;
        if (e >= E) { s = N + src1[e - E]; d = N + dst1[e - E]; }
        else        { s = src0[e];         d = dst0[e]; }
        int b = d >> BSHIFT;
        int pos = atomicAdd(&cur[b], 1);
        ebuf[pos] = ((d & (BNODES - 1)) << 17) | s;
    }
}

__global__ void bucket_sort(const int* __restrict__ ebuf_in, const int* __restrict__ bbase,
                            int* __restrict__ ebuf_out, int* __restrict__ rowptr,
                            float* __restrict__ dinv, float* __restrict__ rsb, int n2) {
    __shared__ int hist[BNODES];
    __shared__ int scan[BNODES];
    __shared__ int cur[BNODES];
    int b = blockIdx.x;
    int node0 = b << BSHIFT;
    int beg = bbase[b];
    int end = bbase[b + 1];
    int t = threadIdx.x;
    if (t < BNODES) hist[t] = 0;
    __syncthreads();
    for (int e = beg + t; e < end; e += 256)
        atomicAdd(&hist[(unsigned)ebuf_in[e] >> 17], 1);
    __syncthreads();
    if (t < BNODES) scan[t] = hist[t];
    __syncthreads();
    #pragma unroll
    for (int off = 1; off < BNODES; off <<= 1) {
        int a = (t < BNODES && t >= off) ? scan[t - off] : 0;
        __syncthreads();
        if (t < BNODES) scan[t] += a;
        __syncthreads();
    }
    int nvalid = min(BNODES, n2 - node0);
    if (t < nvalid) {
        int d = hist[t];
        int incl = scan[t];
        rowptr[node0 + t + 1] = beg + incl;
        cur[t] = beg + incl - d;
        float df = (float)(d < 1 ? 1 : d);
        float sq = sqrtf(df);
        rsb[node0 + t] = sq;
        dinv[node0 + t] = 1.0f / sq;
    }
    __syncthreads();
    for (int e = beg + t; e < end; e += 256) {
        int p = ebuf_in[e];
        int pos = atomicAdd(&cur[(unsigned)p >> 17], 1);
        ebuf_out[pos] = (p & 0x1FFFF) << 6;
    }
}

// ---------------------------------------------------------------------------
// SpMM (measured-best round-9 form). One wave per node, lane = feature;
// scalar beg/end via readfirstlane; 8 gathers in flight.
// ---------------------------------------------------------------------------
__global__ void spmm_s(const u16* __restrict__ Fin, u16* __restrict__ Fout,
                       const int* __restrict__ rowptr, const int* __restrict__ epay,
                       const float* __restrict__ dinv, int n2) {
    int u = (blockIdx.x * blockDim.x + threadIdx.x) >> 6;
    int j = threadIdx.x & 63;
    if (u >= n2) return;
    int beg = __builtin_amdgcn_readfirstlane(rowptr[u]);
    int end = __builtin_amdgcn_readfirstlane(rowptr[u + 1]);
    const u16* base = Fin + j;
    float a0 = 0.f, a1 = 0.f, a2 = 0.f, a3 = 0.f;
    int e = beg;
    for (; e + 8 <= end; e += 8) {
        int o0 = epay[e + 0], o1 = epay[e + 1], o2 = epay[e + 2], o3 = epay[e + 3];
        int o4 = epay[e + 4], o5 = epay[e + 5], o6 = epay[e + 6], o7 = epay[e + 7];
        u16 v0 = base[o0], v1 = base[o1], v2 = base[o2], v3 = base[o3];
        u16 v4 = base[o4], v5 = base[o5], v6 = base[o6], v7 = base[o7];
        a0 += bf2f(v0); a1 += bf2f(v1); a2 += bf2f(v2); a3 += bf2f(v3);
        a0 += bf2f(v4); a1 += bf2f(v5); a2 += bf2f(v6); a3 += bf2f(v7);
    }
    for (; e + 4 <= end; e += 4) {
        u16 v0 = base[epay[e + 0]], v1 = base[epay[e + 1]];
        u16 v2 = base[epay[e + 2]], v3 = base[epay[e + 3]];
        a0 += bf2f(v0); a1 += bf2f(v1); a2 += bf2f(v2); a3 += bf2f(v3);
    }
    for (; e < end; e++) a0 += bf2f(base[epay[e]]);
    float acc = (a0 + a1) + (a2 + a3);
    float di = dinv[u];
    size_t gi = (size_t)u * 64 + j;
    Fout[gi] = f2bf(bf2f(Fin[gi]) - (di * di) * acc);
}

// ---------------------------------------------------------------------------
// Fused 2-layer MLP via MFMA (unchanged).
// ---------------------------------------------------------------------------
__global__ void mlp_mfma(const float* __restrict__ feat0, const float* __restrict__ feat1,
                         const u16* __restrict__ W1t, const u16* __restrict__ W2t,
                         const float* __restrict__ b1_0, const float* __restrict__ b1_1,
                         const float* __restrict__ b2_0, const float* __restrict__ b2_1,
                         const float* __restrict__ dinv, u16* __restrict__ Hs,
                         int N, int GB) {
    __shared__ u16 tls[4][16 * 64];
    int br = (blockIdx.x >= GB) ? 1 : 0;
    int bb = blockIdx.x - br * GB;
    int lane = threadIdx.x & 63;
    int wv = threadIdx.x >> 6;
    int j = lane & 15;
    int kh = lane >> 4;
    int r0 = bb * 64 + wv * 16;
    const float* feat = br ? feat1 : feat0;
    const float* b1 = br ? b1_1 : b1_0;
    const float* b2 = br ? b2_1 : b2_0;
    const u16* w1t = W1t + br * 64 * 128;
    const u16* w2t = W2t + br * 64 * 64;

    int rr = r0 + j;
    int rc = (rr < N) ? rr : N - 1;

    f32x4 acc[4];
    #pragma unroll
    for (int nt = 0; nt < 4; nt++) acc[nt] = (f32x4){0.f, 0.f, 0.f, 0.f};

    #pragma unroll
    for (int ks = 0; ks < 4; ks++) {
        const float* xp = feat + (size_t)rc * 128 + ks * 32 + kh * 8;
        float4 xa = *reinterpret_cast<const float4*>(xp);
        float4 xb = *reinterpret_cast<const float4*>(xp + 4);
        U16x8 ua;
        ua.q.x = pack2bf(xa.x, xa.y);
        ua.q.y = pack2bf(xa.z, xa.w);
        ua.q.z = pack2bf(xb.x, xb.y);
        ua.q.w = pack2bf(xb.z, xb.w);
        #pragma unroll
        for (int nt = 0; nt < 4; nt++) {
            U16x8 ub;
            ub.q = *reinterpret_cast<const uint4*>(w1t + (nt * 16 + j) * 128 + ks * 32 + kh * 8);
            acc[nt] = __builtin_amdgcn_mfma_f32_16x16x32_bf16(ua.s, ub.s, acc[nt], 0, 0, 0);
        }
    }

    char* tl = reinterpret_cast<char*>(tls[wv]);
    #pragma unroll
    for (int nt = 0; nt < 4; nt++) {
        float bv = b1[nt * 16 + j];
        #pragma unroll
        for (int reg = 0; reg < 4; reg++) {
            int row = kh * 4 + reg;
            int byte = (row * 128 + (nt * 16 + j) * 2) ^ ((row & 7) << 4);
            *reinterpret_cast<u16*>(tl + byte) = f2bf(leaky_f(acc[nt][reg] + bv));
        }
    }
    __syncthreads();

    f32x4 acc2[4];
    #pragma unroll
    for (int nt = 0; nt < 4; nt++) acc2[nt] = (f32x4){0.f, 0.f, 0.f, 0.f};
    #pragma unroll
    for (int ks = 0; ks < 2; ks++) {
        int byte = (j * 128 + (ks * 32 + kh * 8) * 2) ^ ((j & 7) << 4);
        U16x8 ua;
        ua.q = *reinterpret_cast<const uint4*>(tl + byte);
        #pragma unroll
        for (int nt = 0; nt < 4; nt++) {
            U16x8 ub;
            ub.q = *reinterpret_cast<const uint4*>(w2t + (nt * 16 + j) * 64 + ks * 32 + kh * 8);
            acc2[nt] = __builtin_amdgcn_mfma_f32_16x16x32_bf16(ua.s, ub.s, acc2[nt], 0, 0, 0);
        }
    }

    int rowbase = r0 + kh * 4;
    #pragma unroll
    for (int reg = 0; reg < 4; reg++) {
        int row = rowbase + reg;
        if (row < N) {
            float di = dinv[br * N + row];
            u16* o = Hs + (size_t)(br * N + row) * 64 + j;
            #pragma unroll
            for (int nt = 0; nt < 4; nt++)
                o[nt * 16] = f2bf(leaky_f(acc2[nt][reg] + b2[nt * 16 + j]) * di);
        }
    }
}

// ---------------------------------------------------------------------------
// Final GEMM via MFMA (unchanged).
// ---------------------------------------------------------------------------
__global__ void gemmF_mfma(const u16* __restrict__ Hs, const u16* __restrict__ F1s,
                           const u16* __restrict__ F2s, const float* __restrict__ rsb,
                           const u16* __restrict__ Mt, const float* __restrict__ b3,
                           float* __restrict__ out, int N) {
    int lane = threadIdx.x & 63;
    int wv = threadIdx.x >> 6;
    int r0 = blockIdx.x * 64 + wv * 16;
    int j = lane & 15;
    int kh = lane >> 4;

    short8 bfrag[6][4];
    #pragma unroll
    for (int nt = 0; nt < 4; nt++) {
        const u16* mrow = Mt + (size_t)(nt * 16 + j) * 192 + kh * 8;
        #pragma unroll
        for (int ks = 0; ks < 6; ks++) {
            U16x8 u;
            u.q = *reinterpret_cast<const uint4*>(mrow + ks * 32);
            bfrag[ks][nt] = u.s;
        }
    }

    int rr = r0 + j;
    int rc = (rr < N) ? rr : N - 1;
    float s0 = rsb[rc];
    float s1 = rsb[N + rc];

    short8 afrag[6];
    #pragma unroll
    for (int ks = 0; ks < 6; ks++) {
        int pa = ks >> 1;
        const u16* P = (pa == 0) ? Hs : (pa == 1) ? F1s : F2s;
        int koff = (ks & 1) * 32 + kh * 8;
        uint4 x0 = *reinterpret_cast<const uint4*>(P + (size_t)rc * 64 + koff);
        uint4 x1 = *reinterpret_cast<const uint4*>(P + ((size_t)N + rc) * 64 + koff);
        U16x8 u;
        u.q.x = pack2bf(s0 * bflo(x0.x) + s1 * bflo(x1.x),
                        s0 * bfhi(x0.x) + s1 * bfhi(x1.x));
        u.q.y = pack2bf(s0 * bflo(x0.y) + s1 * bflo(x1.y),
                        s0 * bfhi(x0.y) + s1 * bfhi(x1.y));
        u.q.z = pack2bf(s0 * bflo(x0.z) + s1 * bflo(x1.z),
                        s0 * bfhi(x0.z) + s1 * bfhi(x1.z));
        u.q.w = pack2bf(s0 * bflo(x0.w) + s1 * bflo(x1.w),
                        s0 * bfhi(x0.w) + s1 * bfhi(x1.w));
        afrag[ks] = u.s;
    }

    f32x4 acc[4];
    #pragma unroll
    for (int nt = 0; nt < 4; nt++) {
        float bv = 2.f * b3[nt * 16 + j];
        acc[nt] = (f32x4){bv, bv, bv, bv};
    }
    #pragma unroll
    for (int nt = 0; nt < 4; nt++) {
        #pragma unroll
        for (int ks = 0; ks < 6; ks++) {
            acc[nt] = __builtin_amdgcn_mfma_f32_16x16x32_bf16(
                afrag[ks], bfrag[ks][nt], acc[nt], 0, 0, 0);
        }
    }

    int rbase = r0 + kh * 4;
    #pragma unroll
    for (int reg = 0; reg < 4; reg++) {
        int row = rbase + reg;
        if (row < N) {
            float* o = out + (size_t)row * 64 + j;
            #pragma unroll
            for (int nt = 0; nt < 4; nt++)
                o[nt * 16] = leaky_f(acc[nt][reg]);
        }
    }
}

// ---------------------------------------------------------------------------
extern "C" void kernel_launch(void* const* d_in, const int* in_sizes, int n_in,
                              void* d_out, int out_size, void* d_ws, size_t ws_size,
                              hipStream_t stream) {
    const int N = in_sizes[0] / 128;
    const int E = in_sizes[2];
    const int N2 = 2 * N;
    const int NBUCK = (N2 + BNODES - 1) >> BSHIFT;
    const int NCH = (2 * E + CHUNK - 1) / CHUNK;

    const float* feat0 = (const float*)d_in[0];
    const float* feat1 = (const float*)d_in[1];
    const int*   src0  = (const int*)d_in[2];
    const int*   dst0  = (const int*)d_in[3];
    const int*   src1  = (const int*)d_in[4];
    const int*   dst1  = (const int*)d_in[5];
    const float* W1_0  = (const float*)d_in[6];
    const float* b1_0  = (const float*)d_in[7];
    const float* W2_0  = (const float*)d_in[8];
    const float* b2_0  = (const float*)d_in[9];
    const float* W1_1  = (const float*)d_in[10];
    const float* b1_1  = (const float*)d_in[11];
    const float* W2_1  = (const float*)d_in[12];
    const float* b2_1  = (const float*)d_in[13];
    const float* W3    = (const float*)d_in[14];
    const float* b3    = (const float*)d_in[15];
    float* out = (float*)d_out;

    char* p = (char*)d_ws;
    auto alloc = [&](size_t bytes) -> char* {
        char* r = p;
        p += (bytes + 255) & ~(size_t)255;
        return r;
    };
    u16*   Mt        = (u16*)alloc((size_t)64 * 192 * 2);
    u16*   W1t       = (u16*)alloc((size_t)2 * 64 * 128 * 2);
    u16*   W2t       = (u16*)alloc((size_t)2 * 64 * 64 * 2);
    u16*   Hs        = (u16*)alloc((size_t)N2 * 64 * 2);
    u16*   F1s       = (u16*)alloc((size_t)N2 * 64 * 2);
    u16*   F2s       = (u16*)alloc((size_t)N2 * 64 * 2);
    float* dinv      = (float*)alloc((size_t)N2 * 4);
    float* rsb       = (float*)alloc((size_t)N2 * 4);
    int*   rowptr    = (int*)alloc((size_t)(N2 + 1) * 4);
    int*   bcnt      = (int*)alloc((size_t)NBUCK * 4);
    int*   bbase     = (int*)alloc((size_t)(NBUCK + 1) * 4);
    int*   bcursor   = (int*)alloc((size_t)NBUCK * 4);
    int*   ebuf1     = (int*)alloc((size_t)2 * E * 4);
    int*   ebuf2     = (int*)alloc((size_t)2 * E * 4);
    (void)ws_size; (void)n_in; (void)out_size;

    const int GB64 = (N + 63) / 64;

    prep_all<<<(16384 + 255) / 256, 256, 0, stream>>>(
        W3, W1_0, W1_1, W2_0, W2_1, Mt, W1t, W2t, bcnt, NBUCK);

    // --- graph build (round-10 proven form) ---
    bcount<<<NCH, 256, 0, stream>>>(dst0, dst1, bcnt, N, E, NBUCK);
    bscan<<<1, 1024, 0, stream>>>(bcnt, bbase, bcursor, rowptr, NBUCK);
    bucket_scatter<<<NCH, 256, 0, stream>>>(src0, dst0, src1, dst1, bcursor, ebuf1, N, E, NBUCK);
    bucket_sort<<<NBUCK, 256, 0, stream>>>(ebuf1, bbase, ebuf2, rowptr, dinv, rsb, N2);

    // --- fused MLP (both branches), MFMA ---
    mlp_mfma<<<2 * GB64, 256, 0, stream>>>(feat0, feat1, W1t, W2t,
                                           b1_0, b1_1, b2_0, b2_1, dinv, Hs, N, GB64);

    // --- polynomial propagation (bf16, node-sorted CSR) ---
    spmm_s<<<(N2 * 64 + 255) / 256, 256, 0, stream>>>(Hs, F1s, rowptr, ebuf2, dinv, N2);
    spmm_s<<<(N2 * 64 + 255) / 256, 256, 0, stream>>>(F1s, F2s, rowptr, ebuf2, dinv, N2);

    // --- final GEMM via MFMA, branch-folded ---
    gemmF_mfma<<<(N + 63) / 64, 256, 0, stream>>>(Hs, F1s, F2s, rsb, Mt, b3, out, N);
}